// Round 8
// baseline (242.400 us; speedup 1.0000x reference)
//
#include <hip/hip_runtime.h>
#include <math.h>

#define G_MAX 512   // LDS capacity for GT boxes; setup uses G=300
#define SPLIT 4     // threads per anchor (g-loop split)
#define NBINS 4096  // counting-sort bins over ax0 in [-128, 1152)

// ---------------- workspace layout (bytes) ----------------
// 0      : double acc[7*16]            (zeroed by memset)
// 896    : uint   cnt                  (zeroed)
// 1024   : uint   binCount[NBINS]      (zeroed)
// 17408  : uint   cursor[NBINS]
// 33792  : float4 sgt[n][G_MAX]        (gt sorted by x0; x0,y0,x1+1,y1+1)
// 50176  : float  sga[n][G_MAX]        (area; 1e30 = invalid/padding)
// 54272  : float  maxW[n]              (max gt width x1p-x0)
// 54336  : int    perm[A]              (anchor ids sorted by ax0 bin)

__device__ __forceinline__ int binOf(float ax0) {
  float t = (ax0 + 128.0f) * ((float)NBINS / 1280.0f);
  int b = (int)t;
  b = b < 0 ? 0 : b;
  return b > NBINS - 1 ? NBINS - 1 : b;
}

__global__ __launch_bounds__(256) void k_hist(const float* __restrict__ anchors, int A,
                                              unsigned int* __restrict__ binCount) {
  int i = blockIdx.x * 256 + threadIdx.x;
  if (i < A) atomicAdd(&binCount[binOf(anchors[i * 4])], 1u);
}

__global__ __launch_bounds__(1024) void k_scan(const unsigned int* __restrict__ binCount,
                                               unsigned int* __restrict__ cursor) {
  __shared__ unsigned int part[1024];
  int t = threadIdx.x;
  unsigned int c0 = binCount[4 * t + 0], c1 = binCount[4 * t + 1];
  unsigned int c2 = binCount[4 * t + 2], c3 = binCount[4 * t + 3];
  unsigned int s = c0 + c1 + c2 + c3;
  part[t] = s;
  __syncthreads();
  for (int o = 1; o < 1024; o <<= 1) {
    unsigned int v = (t >= o) ? part[t - o] : 0u;
    __syncthreads();
    part[t] += v;
    __syncthreads();
  }
  unsigned int excl = part[t] - s;  // exclusive prefix of this 4-bin group
  cursor[4 * t + 0] = excl;
  cursor[4 * t + 1] = excl + c0;
  cursor[4 * t + 2] = excl + c0 + c1;
  cursor[4 * t + 3] = excl + c0 + c1 + c2;
}

__global__ __launch_bounds__(256) void k_scatter(const float* __restrict__ anchors, int A,
                                                 unsigned int* __restrict__ cursor,
                                                 int* __restrict__ perm) {
  int i = blockIdx.x * 256 + threadIdx.x;
  if (i < A) {
    unsigned int pos = atomicAdd(&cursor[binOf(anchors[i * 4])], 1u);
    perm[pos] = i;  // within-bin order arbitrary: loss is permutation-invariant
  }
}

// One block per image: bitonic-sort G_MAX gt slots by x0; padding sorts to end.
__global__ __launch_bounds__(256) void k_sortgt(const float* __restrict__ boxes, int G,
                                                float4* __restrict__ sgt,
                                                float* __restrict__ sga,
                                                float* __restrict__ maxW) {
  __shared__ float kx[G_MAX], ky[G_MAX], kz[G_MAX], kw[G_MAX], ka[G_MAX];
  __shared__ float red[256];
  int img = blockIdx.x;
  const float* gtb = boxes + (size_t)img * G * 5;
  float wmax = 0.f;
  for (int g = threadIdx.x; g < G_MAX; g += 256) {
    if (g < G) {
      float x0 = gtb[g * 5 + 0], y0 = gtb[g * 5 + 1];
      float x1 = gtb[g * 5 + 2], y1 = gtb[g * 5 + 3];
      float lb = gtb[g * 5 + 4];
      kx[g] = x0; ky[g] = y0; kz[g] = x1 + 1.0f; kw[g] = y1 + 1.0f;
      ka[g] = (lb != -1.0f) ? (x1 - x0 + 1.0f) * (y1 - y0 + 1.0f) : 1e30f;
      wmax = fmaxf(wmax, (x1 + 1.0f) - x0);
    } else {
      // padding: sorts last (x0=3e38, outside any window); zero-overlap box
      kx[g] = 3e38f; ky[g] = 0.f; kz[g] = -3e38f; kw[g] = 1.f; ka[g] = 1e30f;
    }
  }
  red[threadIdx.x] = wmax;
  __syncthreads();
  for (int k = 2; k <= G_MAX; k <<= 1) {
    for (int j = k >> 1; j > 0; j >>= 1) {
      int t = threadIdx.x;
      int i = 2 * t - (t & (j - 1));
      int l = i + j;
      bool up = ((i & k) == 0);
      if ((kx[i] > kx[l]) == up) {
        float tmp;
        tmp = kx[i]; kx[i] = kx[l]; kx[l] = tmp;
        tmp = ky[i]; ky[i] = ky[l]; ky[l] = tmp;
        tmp = kz[i]; kz[i] = kz[l]; kz[l] = tmp;
        tmp = kw[i]; kw[i] = kw[l]; kw[l] = tmp;
        tmp = ka[i]; ka[i] = ka[l]; ka[l] = tmp;
      }
      __syncthreads();
    }
  }
  for (int g = threadIdx.x; g < G_MAX; g += 256) {
    sgt[img * G_MAX + g] = make_float4(kx[g], ky[g], kz[g], kw[g]);
    sga[img * G_MAX + g] = ka[g];
  }
  for (int o = 128; o > 0; o >>= 1) {
    __syncthreads();
    if (threadIdx.x < o) red[threadIdx.x] = fmaxf(red[threadIdx.x], red[threadIdx.x + o]);
  }
  __syncthreads();
  if (threadIdx.x == 0) maxW[img] = red[0];
}

__device__ __forceinline__ float waveSum(float v) {
#pragma unroll
  for (int o = 32; o > 0; o >>= 1) v += __shfl_down(v, o, 64);
  return v;
}

// smooth-L1 with sigma=3 (s2=9)
__device__ __forceinline__ float huber9(float x) {
  float ax = fabsf(x);
  return (ax < (1.0f / 9.0f)) ? 4.5f * x * x : ax - (0.5f / 9.0f);
}

// Exact IoU in the reference's op order. g = (x0, y0, x1+1, y1+1)
__device__ __forceinline__ float iouExact(float bx0, float by0, float bx1, float by1,
                                          float areab, float4 g, float areag) {
  float gx1 = g.z - 1.0f, gy1 = g.w - 1.0f;
  float iw = fminf(bx1, gx1) - fmaxf(bx0, g.x) + 1.0f;
  float ih = fminf(by1, gy1) - fmaxf(by0, g.y) + 1.0f;
  float inter = fmaxf(iw, 0.f) * fmaxf(ih, 0.f);
  float uni = areab + areag - inter;
  return inter / fmaxf(uni, 1.0f);
}

// Inverse comparison key (R5/R6 proven): key=(areaB+areaG)*rcp(inter),
// inter=max(iw,0)*ih (one-clamp); argmax iou == argmin key as uint; negative/
// inf keys = zero-overlap class (output-invariant internal order). Low 9 bits
// carry sorted gt index; min-ties -> smallest sorted index.
__device__ __forceinline__ uint32_t packKey(float x0, float y0, float x1p, float y1p,
                                            float area, float4 gb, float ga,
                                            uint32_t g) {
  float iw = fminf(x1p, gb.z) - fmaxf(x0, gb.x);
  float ih = fminf(y1p, gb.w) - fmaxf(y0, gb.y);
  float inter = fmaxf(iw, 0.f) * ih;
  float key = (area + ga) * __builtin_amdgcn_rcpf(inter);
  return (__float_as_uint(key) & 0xFFFFFE00u) | g;
}

__global__ __launch_bounds__(256) void retina_main(
    const float* __restrict__ pred_cls, const float* __restrict__ rpn_num,
    const float* __restrict__ pred_reg, const float* __restrict__ anchors,
    const float* __restrict__ rpn_iou,
    const float4* __restrict__ sgt, const float* __restrict__ sga,
    const float* __restrict__ maxWp, const int* __restrict__ perm,
    int A, int G, int totalBlocks,
    double* __restrict__ acc, unsigned int* __restrict__ cnt,
    float* __restrict__ out) {
  __shared__ float4 sBox[G_MAX];
  __shared__ float sA[G_MAX];
  __shared__ float sRed[4][7];
  __shared__ int sLast;

  const int img = blockIdx.y;
  const int seg = threadIdx.x & (SPLIT - 1);
  const int al = threadIdx.x >> 2;
  const int i = blockIdx.x * 64 + al;
  const int ip = (i < A) ? i : (A - 1);
  const int ic = perm[ip];  // spatially-sorted anchor id

  // stage pre-sorted gts (coalesced)
  for (int g = threadIdx.x; g < G_MAX; g += 256) {
    sBox[g] = sgt[img * G_MAX + g];
    sA[g] = sga[img * G_MAX + g];
  }
  __syncthreads();

  float t_cls = 0.f, t_bbox = 0.f, t_iou = 0.f, t_num = 0.f;
  float t_npos = 0.f, t_nfg = 0.f, t_ncnt = 0.f;

  const float BBOX_CLIP = 4.1351666f;  // log(1000/16)

  float ax0 = anchors[ic * 4 + 0], ay0 = anchors[ic * 4 + 1];
  float ax1 = anchors[ic * 4 + 2], ay1 = anchors[ic * 4 + 3];
  float aw = ax1 - ax0 + 1.0f, ah = ay1 - ay0 + 1.0f;
  float areaa = aw * ah;
  float acx = ax0 + 0.5f * aw, acy = ay0 + 0.5f * ah;
  float ax1p = ax1 + 1.0f, ay1p = ay1 + 1.0f;

  const float* dp = pred_reg + ((size_t)img * A + ic) * 8;
  float d0 = dp[0], d1 = dp[1], d2 = dp[2], d3 = dp[3];
  float d4 = dp[4], d5 = dp[5], d6 = dp[6], d7 = dp[7];

  float pcv0 = 0.f, pcv1 = 0.f, riv0 = 0.f, riv1 = 0.f, sn0 = 0.f, sn1 = 0.f;
  if (seg == 0) {
    const float* pc = pred_cls + ((size_t)img * A + ic) * 2;
    pcv0 = pc[0]; pcv1 = pc[1];
    const float* ri = rpn_iou + ((size_t)img * A + ic) * 2;
    riv0 = ri[0]; riv1 = ri[1];
    const float* sp = rpn_num + ((size_t)img * A + ic) * 2;
    sn0 = sp[0]; sn1 = sp[1];
  }

  float p0cx = acx + d0 * aw, p0cy = acy + d1 * ah;
  float p0w = aw * expf(fminf(d2, BBOX_CLIP));
  float p0h = ah * expf(fminf(d3, BBOX_CLIP));
  float b0x0 = p0cx - 0.5f * p0w, b0y0 = p0cy - 0.5f * p0h;
  float b0x1 = p0cx + 0.5f * p0w, b0y1 = p0cy + 0.5f * p0h;
  float area0 = (b0x1 - b0x0 + 1.0f) * (b0y1 - b0y0 + 1.0f);
  float b0x1p = b0x1 + 1.0f, b0y1p = b0y1 + 1.0f;

  float p1cx = acx + d4 * aw, p1cy = acy + d5 * ah;
  float p1w = aw * expf(fminf(d6, BBOX_CLIP));
  float p1h = ah * expf(fminf(d7, BBOX_CLIP));
  float b1x0 = p1cx - 0.5f * p1w, b1y0 = p1cy - 0.5f * p1h;
  float b1x1 = p1cx + 0.5f * p1w, b1y1 = p1cy + 0.5f * p1h;
  float area1 = (b1x1 - b1x0 + 1.0f) * (b1y1 - b1y0 + 1.0f);
  float b1x1p = b1x1 + 1.0f, b1y1p = b1y1 + 1.0f;

  // per-wave x-window: any gt outside has inter<=0 for every box in the wave
  float bxlo = fminf(ax0, fminf(b0x0, b1x0));
  float bxhi = fmaxf(ax1p, fmaxf(b0x1p, b1x1p));
#pragma unroll
  for (int o = 32; o > 0; o >>= 1) {
    bxlo = fminf(bxlo, __shfl_xor(bxlo, o, 64));
    bxhi = fmaxf(bxhi, __shfl_xor(bxhi, o, 64));
  }
  float loB = bxlo - maxWp[img];
  int s, e;
  { int lo = 0, hi = G_MAX;
    while (lo < hi) { int m = (lo + hi) >> 1; if (sBox[m].x < loB) lo = m + 1; else hi = m; }
    s = lo; }
  { int lo = 0, hi = G_MAX;
    while (lo < hi) { int m = (lo + hi) >> 1; if (sBox[m].x < bxhi) lo = m + 1; else hi = m; }
    e = lo; }

  uint32_t an1 = 0xFFFFFFFFu, an2 = 0xFFFFFFFFu;
  uint32_t am = 0xFFFFFFFFu;
  uint32_t bk1 = 0xFFFFFFFFu, bk2 = 0xFFFFFFFFu;

#pragma unroll 4
  for (int g = s + seg; g < e; g += SPLIT) {
    float4 gb = sBox[g];
    float ga = sA[g];
    uint32_t gu = (uint32_t)g;
    {
      uint32_t p = packKey(ax0, ay0, ax1p, ay1p, areaa, gb, ga, gu);
      uint32_t hi = max(p, an1);
      an1 = min(an1, p);
      an2 = min(an2, hi);
    }
    {
      uint32_t p = packKey(b0x0, b0y0, b0x1p, b0y1p, area0, gb, ga, gu);
      am = min(am, p);
    }
    {
      uint32_t p = packKey(b1x0, b1y0, b1x1p, b1y1p, area1, gb, ga, gu);
      uint32_t hi = max(p, bk1);
      bk1 = min(bk1, p);
      bk2 = min(bk2, hi);
    }
  }

#pragma unroll
  for (int m = 1; m <= 2; m <<= 1) {
    uint32_t o1 = (uint32_t)__shfl_xor((int)an1, m, 64);
    uint32_t o2 = (uint32_t)__shfl_xor((int)an2, m, 64);
    uint32_t hi = max(an1, o1);
    an1 = min(an1, o1);
    an2 = min(min(an2, o2), hi);

    am = min(am, (uint32_t)__shfl_xor((int)am, m, 64));

    uint32_t q1 = (uint32_t)__shfl_xor((int)bk1, m, 64);
    uint32_t q2 = (uint32_t)__shfl_xor((int)bk2, m, 64);
    uint32_t hib = max(bk1, q1);
    bk1 = min(bk1, q1);
    bk2 = min(min(bk2, q2), hib);
  }

  if (seg == 0 && i < A) {
    // sorted-domain winning indices; empty tracker -> 511 = padding (inert)
    int i0 = (int)(an1 & 0x1FFu);
    int i1 = (int)(an2 & 0x1FFu);
    int ai = (int)(am & 0x1FFu);
    int bi = (int)(bk1 & 0x1FFu);
    int bi2 = (int)(bk2 & 0x1FFu);

    float4 g0 = sBox[i0]; float a0 = sA[i0]; bool val0 = a0 < 1e29f;
    float v0 = val0 ? iouExact(ax0, ay0, ax1, ay1, areaa, g0, a0) : -1.0f;
    float4 g1 = sBox[i1]; float a1 = sA[i1]; bool val1 = a1 < 1e29f;
    float v1 = val1 ? iouExact(ax0, ay0, ax1, ay1, areaa, g1, a1) : -1.0f;
    float4 ga4 = sBox[ai]; float aav = sA[ai];
    float aval = (aav < 1e29f) ? iouExact(b0x0, b0y0, b0x1, b0y1, area0, ga4, aav) : 0.0f;
    int bIdx = (ai == bi) ? bi2 : bi;
    float4 gb4 = sBox[bIdx]; float abv = sA[bIdx];
    float bval = (abv < 1e29f) ? iouExact(b1x0, b1y0, b1x1, b1y1, area1, gb4, abv) : 0.0f;

    float la = (v0 >= 0.5f) ? 1.0f : ((v0 < 0.4f) ? 0.0f : -1.0f);
    float lbv = (v1 >= 0.5f) ? 1.0f : ((v1 < 0.4f) ? 0.0f : -1.0f);
    float lab0 = la;
    float lab1 = lbv - (((la == 0.0f) && (lbv != 0.0f)) ? 1.0f : 0.0f);

    {
      float p = pcv0;
      if (lab0 != -1.0f) {
        float l = (lab0 == 1.0f) ? 0.25f * (1.0f - p) * (1.0f - p) * logf(p)
                                 : 0.75f * p * p * logf(1.0f - p);
        t_cls -= l;
      }
      if (lab0 > 0.f) t_npos += 1.f;
      float q = pcv1;
      if (lab1 != -1.0f) {
        float l = (lab1 == 1.0f) ? 0.25f * (1.0f - q) * (1.0f - q) * logf(q)
                                 : 0.75f * q * q * logf(1.0f - q);
        t_cls -= l;
      }
      if (lab1 > 0.f) t_npos += 1.f;
    }

    bool fg0 = (lab0 != 0.0f) && (lab0 != -1.0f);
    bool fg1 = (lab1 != 0.0f) && (lab1 != -1.0f);

    float raw = __builtin_amdgcn_rcpf(aw), rah = __builtin_amdgcn_rcpf(ah);

    if (fg0) {
      float mx1 = g0.z - 1.0f, my1 = g0.w - 1.0f;
      float gw = mx1 - g0.x + 1.0f, gh = my1 - g0.y + 1.0f;
      float gcx = g0.x + 0.5f * gw, gcy = g0.y + 0.5f * gh;
      float t0 = (gcx - acx) * raw, t1v = (gcy - acy) * rah;
      float t2 = logf(gw * raw), t3 = logf(gh * rah);
      t_bbox += huber9(d0 - t0) + huber9(d1 - t1v) + huber9(d2 - t2) + huber9(d3 - t3);
      t_nfg += 1.f;
    }
    if (fg1) {
      float mx1 = g1.z - 1.0f, my1 = g1.w - 1.0f;
      float gw = mx1 - g1.x + 1.0f, gh = my1 - g1.y + 1.0f;
      float gcx = g1.x + 0.5f * gw, gcy = g1.y + 0.5f * gh;
      float t0 = (gcx - acx) * raw, t1v = (gcy - acy) * rah;
      float t2 = logf(gw * raw), t3 = logf(gh * rah);
      t_bbox += huber9(d4 - t0) + huber9(d5 - t1v) + huber9(d6 - t2) + huber9(d7 - t3);
      t_nfg += 1.f;
    }

    if (fg0) t_iou += fabsf(riv0 - aval);
    if (fg1) t_iou += fabsf(riv1 - fmaxf(bval, 0.0f));

    {
      int nl = ((lab0 > 0.f) ? 1 : 0) + ((lab1 > 0.f) ? 1 : 0) - 1;
      if (nl != -1) {
        float m = fmaxf(sn0, sn1);
        float lse = m + logf(expf(sn0 - m) + expf(sn1 - m));
        float picked = ((nl == 0) ? sn0 : sn1) - lse;
        t_num -= picked;
        t_ncnt += 1.f;
      }
    }
  }

  float vals[7] = {t_cls, t_bbox, t_iou, t_num, t_npos, t_nfg, t_ncnt};
  int lane = threadIdx.x & 63;
  int wid = threadIdx.x >> 6;
#pragma unroll
  for (int k = 0; k < 7; ++k) {
    float sv = waveSum(vals[k]);
    if (lane == 0) sRed[wid][k] = sv;
  }
  __syncthreads();
  if (threadIdx.x < 7) {
    double sv = (double)sRed[0][threadIdx.x] + (double)sRed[1][threadIdx.x] +
                (double)sRed[2][threadIdx.x] + (double)sRed[3][threadIdx.x];
    atomicAdd(&acc[threadIdx.x * 16], sv);
    __threadfence();
  }
  __syncthreads();
  if (threadIdx.x == 0) {
    unsigned int old = atomicAdd(cnt, 1u);
    sLast = (old == (unsigned int)(totalBlocks - 1)) ? 1 : 0;
  }
  __syncthreads();

  if (sLast && threadIdx.x == 0) {
    __threadfence();
    double cls = atomicAdd(&acc[0 * 16], 0.0);
    double bbox = atomicAdd(&acc[1 * 16], 0.0);
    double iou = atomicAdd(&acc[2 * 16], 0.0);
    double num = atomicAdd(&acc[3 * 16], 0.0);
    double npos = atomicAdd(&acc[4 * 16], 0.0);
    double nfg = atomicAdd(&acc[5 * 16], 0.0);
    double ncnt = atomicAdd(&acc[6 * 16], 0.0);
    double dpos = npos > 1.0 ? npos : 1.0;
    double dfg = nfg > 1.0 ? nfg : 1.0;
    double dcnt = ncnt > 1.0 ? ncnt : 1.0;
    out[0] = (float)(cls / dpos);
    out[1] = (float)(2.0 * bbox / dfg);
    out[2] = (float)(2.0 * iou / dfg);
    out[3] = (float)(num / dcnt);
  }
}

extern "C" void kernel_launch(void* const* d_in, const int* in_sizes, int n_in,
                              void* d_out, int out_size, void* d_ws, size_t ws_size,
                              hipStream_t stream) {
  const float* pred_cls = (const float*)d_in[0];
  const float* rpn_num  = (const float*)d_in[1];
  const float* pred_reg = (const float*)d_in[2];
  const float* anchors  = (const float*)d_in[3];
  const float* rpn_iou  = (const float*)d_in[4];
  const float* boxes    = (const float*)d_in[5];

  int A = in_sizes[3] / 4;
  int n = in_sizes[0] / (2 * A);
  int G = in_sizes[5] / (5 * n);

  char* ws = (char*)d_ws;
  double* acc          = (double*)(ws + 0);
  unsigned int* cnt    = (unsigned int*)(ws + 896);
  unsigned int* binCnt = (unsigned int*)(ws + 1024);
  unsigned int* cursor = (unsigned int*)(ws + 17408);
  float4* sgt          = (float4*)(ws + 33792);
  float* sga           = (float*)(ws + 50176);
  float* maxW          = (float*)(ws + 54272);
  int* perm            = (int*)(ws + 54336);

  hipMemsetAsync(d_ws, 0, 17408, stream);  // acc + cnt + binCount

  int tb = (A + 255) / 256;
  k_hist<<<tb, 256, 0, stream>>>(anchors, A, binCnt);
  k_scan<<<1, 1024, 0, stream>>>(binCnt, cursor);
  k_scatter<<<tb, 256, 0, stream>>>(anchors, A, cursor, perm);
  k_sortgt<<<n, 256, 0, stream>>>(boxes, G, sgt, sga, maxW);

  int nBx = (A + 63) / 64;
  int totalBlocks = nBx * n;
  dim3 grid(nBx, n, 1);
  retina_main<<<grid, dim3(256, 1, 1), 0, stream>>>(
      pred_cls, rpn_num, pred_reg, anchors, rpn_iou,
      sgt, sga, maxW, perm, A, G, totalBlocks, acc, cnt, (float*)d_out);
}